// Round 11
// baseline (170.745 us; speedup 1.0000x reference)
//
#include <hip/hip_runtime.h>

// Problem constants (from reference setup_inputs)
#define BB   8
#define PP   16384
#define KK   16384
#define NN   16
#define CIN  64
#define REL  3
#define CC   67
#define OUTC 64
#define PITCH_US 104       // ushorts per staged row: 96 data + 8 pad = 208 B

// History: r2-4 94us (W re-read per row); r5 76us (MFMA matvec); r6 87us
// (grid tail); r7 61us (quad-row gather); r9 56us (batched MLP); r10 45.5us
// main (bf16 feats pre-pass halves gather CLs; FETCH 82->31MB, slab fully
// L2-resident). Scored metric = ~100us fixed harness overhead + sum of our
// dispatches, so the target is prepass(~10us floor) + main.
// r10 counters: VALU 30%, HBM 18%, MFMA 1.2%, occupancy 30% (<< the 50%
// configured) -- every pipe idle. Two candidate limits: (a) per-CU MSHR
// pool saturated (structural), (b) under-saturation: in-flight-gather duty
// cycle ~40% per wave x only ~10 waves/CU time-avg resident.
//
// Round 11 tests (b) with ONE variable: occupancy doubling.
//  * 512-thread blocks (8 waves), 1 group of 16 rows per wave, 1024 blocks
//    -> 4 blocks/CU x 8 waves = 32 waves/CU (hw max), 2x r10's wave count.
//  * LDS: 13312 (W, shared by 8 waves) + 8x16x208 staging = 39936 B
//    -> exactly 4 blocks/CU (159744 <= 163840).
//  * __launch_bounds__(512,8) caps VGPR at 64 (r10 used 60, same per-wave
//    code). If VGPR>64/scratch appears: spill -> revert.
// Everything else byte-identical to r10 for clean attribution.

typedef short s16x8 __attribute__((ext_vector_type(8)));   // 8 bf16 = 4 VGPRs
typedef float f32x4 __attribute__((ext_vector_type(4)));   // MFMA accum
typedef unsigned int u32x2 __attribute__((ext_vector_type(2)));

static __device__ __forceinline__ unsigned short bf16_rne(float f) {
    unsigned int u = __float_as_uint(f);
    u += 0x7FFF + ((u >> 16) & 1);          // round-to-nearest-even
    return (unsigned short)(u >> 16);
}

template <int PAT>
static __device__ __forceinline__ float swz_add(float v) {
    return v + __int_as_float(
        __builtin_amdgcn_ds_swizzle(__float_as_int(v), PAT));
}

// ---- pre-pass: feats fp32 -> bf16 (RNE) into workspace ----
__global__ __launch_bounds__(256) void feats_to_bf16_kernel(
    const float* __restrict__ f, unsigned short* __restrict__ o)
{
    const int i = blockIdx.x * 256 + threadIdx.x;   // one float4 per thread
    const float4 v = ((const float4*)f)[i];         // 16B coalesced read
    ushort4 r;
    r.x = bf16_rne(v.x); r.y = bf16_rne(v.y);
    r.z = bf16_rne(v.z); r.w = bf16_rne(v.w);
    ((ushort4*)o)[i] = r;                           // 8B coalesced write
}

__global__ __launch_bounds__(512, 8) void graphconv_kernel(
    const unsigned short* __restrict__ fbf16,// [B, P, CIN] bf16 (workspace)
    const int*   __restrict__ n_idxs,        // [B, K, N]
    const float* __restrict__ neighbor_rel,  // [B, K, N, REL]
    const int*   __restrict__ neighbor_valid,// [B, K, N]
    const float* __restrict__ Wm,            // [OUTC, CC]
    const float* __restrict__ bvec,          // [OUTC]
    float*       __restrict__ out)           // [B, K, OUTC]
{
    __shared__ __align__(16) unsigned short Wbf[OUTC * PITCH_US];     // 13312 B
    __shared__ __align__(16) unsigned short Stile[8 * 16 * PITCH_US]; // 26624 B

    const int tid = threadIdx.x;

    // ---- one-time: W -> bf16 into LDS, B-layout, cols 67..95 zeroed ----
    {
        unsigned int* w32 = (unsigned int*)Wbf;
        for (int j = tid; j < OUTC * (PITCH_US / 2); j += 512) {
            const int o = j / (PITCH_US / 2);
            const int d = j - o * (PITCH_US / 2);
            const int c0 = 2 * d, c1 = 2 * d + 1;
            const float w0 = (c0 < CC) ? Wm[o * CC + c0] : 0.0f;
            const float w1 = (c1 < CC) ? Wm[o * CC + c1] : 0.0f;
            w32[j] = (unsigned int)bf16_rne(w0) |
                     ((unsigned int)bf16_rne(w1) << 16);
        }
    }
    __syncthreads();

    const int lane = tid & 63;
    const int wave = __builtin_amdgcn_readfirstlane(tid >> 6);   // 0..7
    unsigned short* Sw = &Stile[wave * 16 * PITCH_US];

    // zero own tile once (pad cols 68..95 must stay 0.0 for the MFMA)
    {
        unsigned int* s32 = (unsigned int*)Sw;
        for (int j = lane; j < 16 * (PITCH_US / 2); j += 64) s32[j] = 0u;
    }

    const int b   = blockIdx.x & 7;          // XCD-bound batch (verified)
    const int bib = blockIdx.x >> 3;         // 0..127 within batch
    const unsigned short* fb = fbf16 + (size_t)b * ((size_t)PP * CIN);

    const int q     = lane & 15;             // channel quarter (cols 4q..4q+3)
    const int permb = (lane & 48) << 2;      // byte index of segment start

    const int kg = (bib * 8 + wave) * 16;    // wave's 16 rows (one group)
    const size_t rg = (size_t)b * KK + (size_t)kg;

    // ---- all 4 quads' metadata up-front (off the critical chain) ----
    int   vld[4], idd[4];
    float rl0[4], rl1[4], rl2[4];
#pragma unroll
    for (int qd = 0; qd < 4; ++qd) {
        const size_t rq = rg + (size_t)(qd * 4);
        vld[qd] = neighbor_valid[rq * NN + lane];   // 256B coalesced
        idd[qd] = n_idxs[rq * NN + lane];           // 256B coalesced
        const float* relq = neighbor_rel + rq * (NN * REL);
        rl0[qd] = relq[3 * lane + 0];               // 768B coalesced
        rl1[qd] = relq[3 * lane + 1];
        rl2[qd] = relq[3 * lane + 2];
    }

    // ---- phase 1: 4 quads of 4 rows -> bf16 staging tile ----
    for (int qd = 0; qd < 4; ++qd) {
        const int   cmb = idd[qd] | (vld[qd] << 14);   // id<16384 fits
        const float msf = (float)vld[qd];
        float mr0 = msf * rl0[qd];
        float mr1 = msf * rl1[qd];
        float mr2 = msf * rl2[qd];
        float cnt = msf;

        // all 16 neighbor (id|mask) words first: one bpermute each
        int cm[NN];
#pragma unroll
        for (int n = 0; n < NN; ++n)
            cm[n] = __builtin_amdgcn_ds_bpermute(permb + 4 * n, cmb);

        // issue ALL 16 bf16 gathers (uint2 = 8B/lane; 32 VGPRs live);
        // each instr touches 4 rows x 128B = 8 CLs
        u32x2 gv[NN];
#pragma unroll
        for (int n = 0; n < NN; ++n) {
            const int off = ((cm[n] & 0x3FFF) << 6) + 4 * q; // ushort elems
            gv[n] = *(const u32x2*)(fb + off);
        }
        __builtin_amdgcn_sched_barrier(0);        // loads stay hoisted

        float s0 = 0.f, s1 = 0.f, s2 = 0.f, s3 = 0.f;
#pragma unroll
        for (int n = 0; n < NN; ++n) {            // unpack bf16 + fma
            const float m = (float)(cm[n] >> 14);
            const unsigned ux = gv[n].x, uy = gv[n].y;
            s0 = fmaf(m, __uint_as_float(ux << 16), s0);
            s1 = fmaf(m, __uint_as_float(ux & 0xFFFF0000u), s1);
            s2 = fmaf(m, __uint_as_float(uy << 16), s2);
            s3 = fmaf(m, __uint_as_float(uy & 0xFFFF0000u), s3);
        }

        // segment(16-lane) butterfly: count + 3 masked rel sums
        cnt = swz_add<0x041F>(cnt); mr0 = swz_add<0x041F>(mr0);
        mr1 = swz_add<0x041F>(mr1); mr2 = swz_add<0x041F>(mr2);
        cnt = swz_add<0x081F>(cnt); mr0 = swz_add<0x081F>(mr0);
        mr1 = swz_add<0x081F>(mr1); mr2 = swz_add<0x081F>(mr2);
        cnt = swz_add<0x101F>(cnt); mr0 = swz_add<0x101F>(mr0);
        mr1 = swz_add<0x101F>(mr1); mr2 = swz_add<0x101F>(mr2);
        cnt = swz_add<0x201F>(cnt); mr0 = swz_add<0x201F>(mr0);
        mr1 = swz_add<0x201F>(mr1); mr2 = swz_add<0x201F>(mr2);

        const float inv = (cnt > 0.f) ? (1.0f / cnt) : 0.0f;

        const int rowl = qd * 4 + (lane >> 4);   // row within 16-row tile
        u32x2 pv;
        pv.x = (unsigned)bf16_rne(s0 * inv) |
               ((unsigned)bf16_rne(s1 * inv) << 16);
        pv.y = (unsigned)bf16_rne(s2 * inv) |
               ((unsigned)bf16_rne(s3 * inv) << 16);
        *(u32x2*)(&Sw[rowl * PITCH_US + 4 * q]) = pv;     // ds_write_b64
        if (q == 0) {                      // rel -> ch 64..66 (+0 pad 67)
            u32x2 ev;
            ev.x = (unsigned)bf16_rne(mr0 * inv) |
                   ((unsigned)bf16_rne(mr1 * inv) << 16);
            ev.y = (unsigned)bf16_rne(mr2 * inv);
            *(u32x2*)(&Sw[rowl * PITCH_US + 64]) = ev;
        }
    }

    // ---- phase 2: 16x64 = S(16x96) x W^T(96x64) on the MFMA pipe ----
    f32x4 C0 = {0.f,0.f,0.f,0.f}, C1 = {0.f,0.f,0.f,0.f};
    f32x4 C2 = {0.f,0.f,0.f,0.f}, C3 = {0.f,0.f,0.f,0.f};
#pragma unroll
    for (int p = 0; p < 3; ++p) {
        const int ko = p * 32 + (lane >> 4) * 8;
        const s16x8 A  = *(const s16x8*)&Sw[(lane & 15) * PITCH_US + ko];
        const s16x8 B0 = *(const s16x8*)&Wbf[( 0 + (lane & 15)) * PITCH_US + ko];
        const s16x8 B1 = *(const s16x8*)&Wbf[(16 + (lane & 15)) * PITCH_US + ko];
        const s16x8 B2 = *(const s16x8*)&Wbf[(32 + (lane & 15)) * PITCH_US + ko];
        const s16x8 B3 = *(const s16x8*)&Wbf[(48 + (lane & 15)) * PITCH_US + ko];
        C0 = __builtin_amdgcn_mfma_f32_16x16x32_bf16(A, B0, C0, 0, 0, 0);
        C1 = __builtin_amdgcn_mfma_f32_16x16x32_bf16(A, B1, C1, 0, 0, 0);
        C2 = __builtin_amdgcn_mfma_f32_16x16x32_bf16(A, B2, C2, 0, 0, 0);
        C3 = __builtin_amdgcn_mfma_f32_16x16x32_bf16(A, B3, C3, 0, 0, 0);
    }

    // ---- epilogue: C/D layout col=lane&15, row=(lane>>4)*4+r ----
    const float bias0 = bvec[ 0 + (lane & 15)];
    const float bias1 = bvec[16 + (lane & 15)];
    const float bias2 = bvec[32 + (lane & 15)];
    const float bias3 = bvec[48 + (lane & 15)];
    const int m0 = (lane >> 4) * 4;
    const int oc = lane & 15;
#pragma unroll
    for (int r = 0; r < 4; ++r) {
        const size_t orow = ((size_t)b * KK + (size_t)(kg + m0 + r)) * OUTC;
        out[orow + 0  + oc] = fmaxf(C0[r] + bias0, 0.0f);
        out[orow + 16 + oc] = fmaxf(C1[r] + bias1, 0.0f);
        out[orow + 32 + oc] = fmaxf(C2[r] + bias2, 0.0f);
        out[orow + 48 + oc] = fmaxf(C3[r] + bias3, 0.0f);
    }
}

extern "C" void kernel_launch(void* const* d_in, const int* in_sizes, int n_in,
                              void* d_out, int out_size, void* d_ws, size_t ws_size,
                              hipStream_t stream) {
    // setup_inputs order: keys(0), points(1), feats(2), n_idxs(3),
    // neighbor_rel(4), neighbor_valid(5), W(6), b(7). keys/points unused.
    const float* feats = (const float*)d_in[2];
    const int*   nidx  = (const int*)  d_in[3];
    const float* nrel  = (const float*)d_in[4];
    const int*   nval  = (const int*)  d_in[5];
    const float* Wm    = (const float*)d_in[6];
    const float* bv    = (const float*)d_in[7];
    float* out = (float*)d_out;

    // workspace: bf16 feats image, 8*16384*64*2 = 16.78 MB
    unsigned short* fbf16 = (unsigned short*)d_ws;

    // pre-pass: 8.39M floats / 4 per thread = 2.097M threads = 8192 blocks
    feats_to_bf16_kernel<<<dim3(8192), dim3(256), 0, stream>>>(feats, fbf16);

    // main: 1024 blocks x 512 threads (8 waves). b = blockIdx&7 XCD binding;
    // 128 blocks/batch x 8 waves x 16 rows = 16384 k per batch.
    // 4 blocks/CU exact (LDS 39936x4 = 159744 <= 163840) = 32 waves/CU.
    graphconv_kernel<<<dim3(1024), dim3(512), 0, stream>>>(
        fbf16, nidx, nrel, nval, Wm, bv, out);
}